// Round 4
// 835.583 us; speedup vs baseline: 1.0425x; 1.0425x over previous
//
#include <hip/hip_runtime.h>

#define T_LEN 1024
#define IN_DIM 128
#define HID 64
// LDS row strides in shorts. 160*2B=320B=80 dwords == 16 (mod 32) and
// 96*2B=192B=48 dwords == 16 (mod 32): rows 0,2 occupy banks 0-15 and rows
// 1,3 banks 16-31 on the b128 A-frag reads -> exactly 2-way (free, m136).
// Old strides (136/72 shorts == 4 dwords mod 32) gave 4-way overlap
// (SQ_LDS_BANK_CONFLICT 1.9e7).
#define XSTR 160
#define HSTR 96

typedef __attribute__((ext_vector_type(8))) short short8;
typedef __attribute__((ext_vector_type(4))) float floatx4;
typedef __attribute__((ext_vector_type(2))) float floatx2;

__device__ __forceinline__ unsigned short f2bf(float v) {
    union { float f; unsigned u; } a; a.f = v;
    unsigned r = a.u + 0x7FFFu + ((a.u >> 16) & 1u);  // RNE, no NaN inputs here
    return (unsigned short)(r >> 16);
}

__device__ __forceinline__ short8 cvt8(const float* p) {
    short8 r;
#pragma unroll
    for (int j = 0; j < 8; ++j) r[j] = (short)f2bf(p[j]);
    return r;
}

// fast sigmoid / tanh: v_exp_f32 (2^x) + v_rcp_f32, ~1 ulp each
#define LOG2E 1.44269504088896f
__device__ __forceinline__ float sigm(float x) {
    return __builtin_amdgcn_rcpf(1.0f + __builtin_amdgcn_exp2f(x * -LOG2E));
}
__device__ __forceinline__ float tanh_(float x) {
    return 2.0f * __builtin_amdgcn_rcpf(1.0f + __builtin_amdgcn_exp2f(x * -2.0f * LOG2E)) - 1.0f;
}

// DISCRIMINATOR ROUND: rounds 1-3 (raw s_barrier + lgkm-only waitcnt) all
// died with container failures; the Round-0 baseline with __syncthreads()
// ran fine. This version keeps the two safe optimizations (xacc hoist off
// the recurrent chain + LDS stride fix) but uses plain __syncthreads() to
// separate kernel-induced container death from broken infra.

// One block = 4 batch rows of one direction. 256 blocks = 2 dirs * 128.
// Wave w owns gate classes i,f,g,o for units j=16w..16w+15.
// A-fragment rows are read REPLICATED (row = nloc>>2) so effective A rows are
// {r0 x4, r1 x4, r2 x4, r3 x4}; C row = quad*4+reg then means every lane
// (quad q, col n) holds gates for (batch row q, unit 16w+n) in all 4 acc regs
// -> full-wave epilogue with zero cross-lane traffic.
//
// Software pipeline (per step t, steady state):
//   reads  x_s[cur^1] (= x(t+1))  -> xaccN (input-gate MFMAs for NEXT step)
//   reads  h_s[cur]   (= h(t))    -> acc = xaccC + 2 chained h-MFMAs  [critical]
//   writes h_s[cur^1] (= h(t+1)), x_s[cur] (= x(t+2), from a 2-step-deep
//   global prefetch), then barrier.
// Post-barrier critical chain is ds_read h -> 2 MFMA -> epilogue instead of
// ds_read -> 6 MFMA -> epilogue. Accumulation order (bias, x kf0..3, h kf0..1)
// is unchanged -> bit-identical results to the 868us baseline.
__global__ __launch_bounds__(256, 1) void lstm_bidir(
    const float* __restrict__ x,
    const float* __restrict__ WihF, const float* __restrict__ WhhF, const float* __restrict__ bF,
    const float* __restrict__ WihB, const float* __restrict__ WhhB, const float* __restrict__ bB,
    float* __restrict__ out)
{
    const int tid  = threadIdx.x;
    const int w    = tid >> 6;       // wave id 0..3
    const int lane = tid & 63;
    const int nloc = lane & 15;      // C col / B n index
    const int quad = lane >> 4;      // A/B k = quad*8 + j ; epilogue batch row
    const int bid  = blockIdx.x;
    const int dir  = bid & 1;
    const int b0   = (bid >> 1) * 4;

    const float* Wih  = dir ? WihB : WihF;
    const float* Whh  = dir ? WhhB : WhhF;
    const float* bias = dir ? bB   : bF;

    __shared__ unsigned short x_s[2][4 * XSTR];
    __shared__ unsigned short h_s[2][4 * HSTR];

    for (int i = tid; i < 2 * 4 * HSTR; i += 256) ((unsigned short*)h_s)[i] = 0;

    // ---- Preload weight B-fragments into registers (one-time, ~96 VGPRs) ----
    short8 wihf[4][4];  // [gate class][k-frag of 32]
    short8 whhf[4][2];
    float  bv[4];
#pragma unroll
    for (int gc = 0; gc < 4; ++gc) {
        const int row = gc * 64 + w * 16 + nloc;   // gate index in [0,256)
        bv[gc] = bias[row];
#pragma unroll
        for (int kf = 0; kf < 4; ++kf)
            wihf[gc][kf] = cvt8(Wih + row * IN_DIM + kf * 32 + quad * 8);
#pragma unroll
        for (int kf = 0; kf < 2; ++kf)
            whhf[gc][kf] = cvt8(Whh + row * HID + kf * 32 + quad * 8);
    }

    // ---- x staging: 256 threads x float2 = 4 rows x 128 ----
    const int sr = tid >> 6;            // staging row 0..3
    const int sk = (tid & 63) * 2;      // staging k
    const float* xrow = x + (size_t)(b0 + sr) * T_LEN * IN_DIM + sk;

    auto tmap = [&](int s) {
        int ss = s < T_LEN - 1 ? s : T_LEN - 1;
        return dir ? (T_LEN - 1 - ss) : ss;
    };

    auto stage = [&](int s, int buf) {
        floatx2 v = *(const floatx2*)(xrow + (size_t)tmap(s) * IN_DIM);
        unsigned pack = (unsigned)f2bf(v.x) | ((unsigned)f2bf(v.y) << 16);
        *(unsigned*)&x_s[buf][sr * XSTR + sk] = pack;
    };
    stage(0, 0);               // x(0) -> buf0
    stage(1, 1);               // x(1) -> buf1
    // 2-step-deep global prefetch (consumed 2 barriers after issue)
    floatx2 pfA = *(const floatx2*)(xrow + (size_t)tmap(2) * IN_DIM);
    floatx2 pfB = *(const floatx2*)(xrow + (size_t)tmap(3) * IN_DIM);

    float c = 0.f;             // cell state for (row=quad, unit=16w+nloc)

    __syncthreads();           // h_s zeroed + x(0)/x(1) staged

    // ---- Prologue: xacc for t=0 from x_s[0] ----
    floatx4 xacc0[4], xacc1[4];
    {
        short8 xa[4];
        const unsigned short* xb = &x_s[0][(nloc >> 2) * XSTR + quad * 8];
#pragma unroll
        for (int kf = 0; kf < 4; ++kf) xa[kf] = *(const short8*)(xb + kf * 32);
        // all waves must finish reading x_s[0] before step 0 overwrites it
        // with x(2) -- this barrier closes that read/write race.
        __syncthreads();
#pragma unroll
        for (int gc = 0; gc < 4; ++gc) xacc0[gc] = (floatx4){bv[gc], bv[gc], bv[gc], bv[gc]};
#pragma unroll
        for (int kf = 0; kf < 4; ++kf)
#pragma unroll
            for (int gc = 0; gc < 4; ++gc)
                xacc0[gc] = __builtin_amdgcn_mfma_f32_16x16x32_bf16(xa[kf], wihf[gc][kf], xacc0[gc], 0, 0, 0);
    }

    // epilogue output column: out[(b0+quad)*T*128 + t*128 + dir*64 + 16w + nloc]
    float* outcol = out + ((size_t)(b0 + quad) * T_LEN) * 128 + dir * HID + w * 16 + nloc;

    auto step = [&](int t, int cur, floatx4* xaccC, floatx4* xaccN, floatx2& pf) {
        // issue global prefetch x(t+4) early (consumed at step t+2)
        floatx2 old = pf;      // holds x(t+2), loaded 2 steps ago
        pf = *(const floatx2*)(xrow + (size_t)tmap(t + 4) * IN_DIM);

        // critical ds_reads first: h(t) A-frags
        short8 ha[2];
        const unsigned short* hb = &h_s[cur][(nloc >> 2) * HSTR + quad * 8];
#pragma unroll
        for (int kf = 0; kf < 2; ++kf) ha[kf] = *(const short8*)(hb + kf * 32);

        // x(t+1) A-frags (staged 2 barriers ago into x_s[cur^1])
        short8 xa[4];
        const unsigned short* xb = &x_s[cur ^ 1][(nloc >> 2) * XSTR + quad * 8];
#pragma unroll
        for (int kf = 0; kf < 4; ++kf) xa[kf] = *(const short8*)(xb + kf * 32);

        // critical chain: 2 h-MFMAs on top of precomputed xaccC
        floatx4 acc[4];
#pragma unroll
        for (int gc = 0; gc < 4; ++gc)
            acc[gc] = __builtin_amdgcn_mfma_f32_16x16x32_bf16(ha[0], whhf[gc][0], xaccC[gc], 0, 0, 0);
#pragma unroll
        for (int gc = 0; gc < 4; ++gc)
            acc[gc] = __builtin_amdgcn_mfma_f32_16x16x32_bf16(ha[1], whhf[gc][1], acc[gc], 0, 0, 0);

        // off-critical: input-gate accumulators for step t+1 (fills MFMA pipe
        // while the h chain + epilogue drain)
#pragma unroll
        for (int gc = 0; gc < 4; ++gc) xaccN[gc] = (floatx4){bv[gc], bv[gc], bv[gc], bv[gc]};
#pragma unroll
        for (int kf = 0; kf < 4; ++kf)
#pragma unroll
            for (int gc = 0; gc < 4; ++gc)
                xaccN[gc] = __builtin_amdgcn_mfma_f32_16x16x32_bf16(xa[kf], wihf[gc][kf], xaccN[gc], 0, 0, 0);

        const int tg = tmap(t);
        // every lane: gates for (row=quad, unit=16w+nloc), replicated -> use [0]
        {
            float iv = sigm(acc[0][0]);
            float fv = sigm(acc[1][0]);
            float gv = tanh_(acc[2][0]);
            float ov = sigm(acc[3][0]);
            c = fv * c + iv * gv;
            float hv = ov * tanh_(c);
            outcol[(size_t)tg * 128] = hv;
            h_s[cur ^ 1][quad * HSTR + w * 16 + nloc] = f2bf(hv);
        }
        // stage x(t+2) (prefetched 2 steps ago) into x_s[cur]
        {
            unsigned pack = (unsigned)f2bf(old.x) | ((unsigned)f2bf(old.y) << 16);
            *(unsigned*)&x_s[cur][sr * XSTR + sk] = pack;
        }
        __syncthreads();
    };

    for (int t = 0; t < T_LEN; t += 2) {
        step(t,     0, xacc0, xacc1, pfA);
        step(t + 1, 1, xacc1, xacc0, pfB);
    }
}

extern "C" void kernel_launch(void* const* d_in, const int* in_sizes, int n_in,
                              void* d_out, int out_size, void* d_ws, size_t ws_size,
                              hipStream_t stream) {
    const float* x    = (const float*)d_in[0];
    const float* WihF = (const float*)d_in[1];
    const float* WhhF = (const float*)d_in[2];
    const float* bF   = (const float*)d_in[3];
    const float* WihB = (const float*)d_in[4];
    const float* WhhB = (const float*)d_in[5];
    const float* bB   = (const float*)d_in[6];
    float* out = (float*)d_out;

    lstm_bidir<<<dim3(256), dim3(256), 0, stream>>>(x, WihF, WhhF, bF, WihB, WhhB, bB, out);
}

// Round 5
// 775.072 us; speedup vs baseline: 1.1239x; 1.0781x over previous
//
#include <hip/hip_runtime.h>

#define T_LEN 1024
#define IN_DIM 128
#define HID 64
#define CH 8              // steps per x-stage / out-flush chunk
#define NCH (T_LEN / CH)  // 128 chunks
// LDS row strides. XSTR/HSTR (shorts): 320B/192B == 16 dwords (mod 32) ->
// 2-way bank aliasing on b128 A-frag reads = free (validated R4: conflicts 0).
// OSTR (floats): 288B -> 2-way on the per-step obuf scatter write.
#define XSTR 160
#define HSTR 96
#define OSTR 72

typedef __attribute__((ext_vector_type(8))) short short8;
typedef __attribute__((ext_vector_type(4))) float floatx4;
typedef __attribute__((ext_vector_type(2))) unsigned uintx2;

__device__ __forceinline__ unsigned short f2bf(float v) {
    union { float f; unsigned u; } a; a.f = v;
    unsigned r = a.u + 0x7FFFu + ((a.u >> 16) & 1u);  // RNE, no NaN inputs here
    return (unsigned short)(r >> 16);
}

__device__ __forceinline__ short8 cvt8(const float* p) {
    short8 r;
#pragma unroll
    for (int j = 0; j < 8; ++j) r[j] = (short)f2bf(p[j]);
    return r;
}

// fast sigmoid / tanh: v_exp_f32 (2^x) + v_rcp_f32, ~1 ulp each
#define LOG2E 1.44269504088896f
__device__ __forceinline__ float sigm(float x) {
    return __builtin_amdgcn_rcpf(1.0f + __builtin_amdgcn_exp2f(x * -LOG2E));
}
__device__ __forceinline__ float tanh_(float x) {
    return 2.0f * __builtin_amdgcn_rcpf(1.0f + __builtin_amdgcn_exp2f(x * -2.0f * LOG2E)) - 1.0f;
}

// R4 post-mortem: __syncthreads()'s vmcnt(0) drain at every step barrier was
// ~550cy/step (x prefetch ~900cy HBM latency issued ~350cy before the same
// step's barrier + out-store ack). Raw lgkm-only barriers are empirically
// lethal on this harness (R1-R3: 3/3 container deaths). Fix by RESTRUCTURING:
// steps 1..7 of each 8-step chunk issue ZERO global ops, so their barriers'
// vmcnt(0) is vacuous. All global traffic (x loads for the next chunk, out
// stores of the previous chunk's LDS buffer) happens in step 0 and is drained
// once per chunk (~500cy exposed / 8 = ~63cy/step amortized).
//
// One block = 4 batch rows of one direction. 256 blocks = 2 dirs * 128.
// Wave w owns gate classes i,f,g,o for units j=16w..16w+15.
// A-fragment rows are read REPLICATED (row = nloc>>2), so every lane
// (quad q, col n) holds gates for (batch row q, unit 16w+n) in all 4 acc regs
// -> full-wave epilogue with zero cross-lane traffic.
// Per step t: xaccN (input-gate MFMAs for t+1, off-critical) + critical chain
// ds_read h(t) -> 2 h-MFMAs on precomputed xaccC -> gates -> c,h -> ds_write.
// Accumulation order (bias, x kf0..3, h kf0..1) identical to R4 -> same absmax.
__global__ __launch_bounds__(256, 1) void lstm_bidir(
    const float* __restrict__ x,
    const float* __restrict__ WihF, const float* __restrict__ WhhF, const float* __restrict__ bF,
    const float* __restrict__ WihB, const float* __restrict__ WhhB, const float* __restrict__ bB,
    float* __restrict__ out)
{
    const int tid  = threadIdx.x;
    const int w    = tid >> 6;       // wave id 0..3
    const int lane = tid & 63;
    const int nloc = lane & 15;      // C col / B n index
    const int quad = lane >> 4;      // A/B k = quad*8 + j ; epilogue batch row
    const int bid  = blockIdx.x;
    const int dir  = bid & 1;
    const int b0   = (bid >> 1) * 4;

    const float* Wih  = dir ? WihB : WihF;
    const float* Whh  = dir ? WhhB : WhhF;
    const float* bias = dir ? bB   : bF;

    // LDS: double-buffered 8-step x chunks (20.5KB), double-buffered 8-step
    // out chunks (18.4KB), double-buffered h tile (1.5KB). Total ~40KB.
    __shared__ __align__(16) unsigned short xch[2][CH][4 * XSTR];
    __shared__ __align__(16) unsigned short h_s[2][4 * HSTR];
    __shared__ __align__(16) float obuf[2][CH][4][OSTR];

    for (int i = tid; i < 2 * 4 * HSTR; i += 256) ((unsigned short*)h_s)[i] = 0;

    // ---- Preload weight B-fragments into registers (one-time) ----
    short8 wihf[4][4];  // [gate class][k-frag of 32]
    short8 whhf[4][2];
    float  bv[4];
#pragma unroll
    for (int gc = 0; gc < 4; ++gc) {
        const int row = gc * 64 + w * 16 + nloc;   // gate index in [0,256)
        bv[gc] = bias[row];
#pragma unroll
        for (int kf = 0; kf < 4; ++kf)
            wihf[gc][kf] = cvt8(Wih + row * IN_DIM + kf * 32 + quad * 8);
#pragma unroll
        for (int kf = 0; kf < 2; ++kf)
            whhf[gc][kf] = cvt8(Whh + row * HID + kf * 32 + quad * 8);
    }

    auto tmap = [&](int s) {
        int ss = s < T_LEN - 1 ? s : T_LEN - 1;
        return dir ? (T_LEN - 1 - ss) : ss;
    };

    // ---- chunk staging mapping: thread (g = tid>>5, l32 = tid&31) loads
    // float4 of row i, local step g: 32 lanes x 16B = 512B contiguous ----
    const int g   = tid >> 5;
    const int l32 = tid & 31;

    // Prologue: stage chunk 0 directly (load + cvt + ds_write)
#pragma unroll
    for (int i = 0; i < 4; ++i) {
        floatx4 v = *(const floatx4*)(x + (size_t)(b0 + i) * T_LEN * IN_DIM
                                        + (size_t)tmap(g) * IN_DIM + l32 * 4);
        unsigned lo = (unsigned)f2bf(v.x) | ((unsigned)f2bf(v.y) << 16);
        unsigned hi = (unsigned)f2bf(v.z) | ((unsigned)f2bf(v.w) << 16);
        uintx2 p = {lo, hi};
        *(uintx2*)&xch[0][g][i * XSTR + l32 * 4] = p;
    }

    float c = 0.f;             // cell state for (row=quad, unit=16w+nloc)

    __syncthreads();           // h_s zeroed + chunk 0 staged

    // ---- Prologue: xacc for t=0 from xch[0][0] (not overwritten until
    // chunk 1 writes chunk-2 data, many barriers away -> no extra barrier) ----
    floatx4 xacc0[4], xacc1[4];
    {
        short8 xa[4];
        const unsigned short* xb = &xch[0][0][(nloc >> 2) * XSTR + quad * 8];
#pragma unroll
        for (int kf = 0; kf < 4; ++kf) xa[kf] = *(const short8*)(xb + kf * 32);
#pragma unroll
        for (int gc = 0; gc < 4; ++gc) xacc0[gc] = (floatx4){bv[gc], bv[gc], bv[gc], bv[gc]};
#pragma unroll
        for (int kf = 0; kf < 4; ++kf)
#pragma unroll
            for (int gc = 0; gc < 4; ++gc)
                xacc0[gc] = __builtin_amdgcn_mfma_f32_16x16x32_bf16(xa[kf], wihf[gc][kf], xacc0[gc], 0, 0, 0);
    }

    floatx4 stg[4];            // in-flight next-chunk x (issued sl0, written sl1)

    // flush chunk chkPrev's outputs from obuf to global (32B/thread).
    // thread -> (fs = tid>>5, fr = (tid&31)>>3, fu = (tid&7)*8): 64-unit rows
    // are 256B contiguous in out.
    auto flushPrev = [&](int chkPrev) {
        const int pb  = chkPrev & 1;
        const int fs  = tid >> 5;
        const int fr  = (tid & 31) >> 3;
        const int fu  = (tid & 7) * 8;
        const float* src = &obuf[pb][fs][fr][fu];
        floatx4 v0 = *(const floatx4*)(src);
        floatx4 v1 = *(const floatx4*)(src + 4);
        const int tg = tmap(chkPrev * CH + fs);
        float* dst = out + ((size_t)(b0 + fr) * T_LEN + tg) * 128 + dir * HID + fu;
        *(floatx4*)(dst)     = v0;
        *(floatx4*)(dst + 4) = v1;
    };

    auto step = [&](int sl, int chk, int cbuf, floatx4* xaccC, floatx4* xaccN) {
        const int cur = sl & 1;              // t = chk*8+sl; parity = sl&1

        if (sl == 0) {
            if (chk > 0) flushPrev(chk - 1);             // stores of prev chunk
            if (chk + 1 < NCH) {                         // issue next-chunk loads
                const int tn = (chk + 1) * CH + g;
#pragma unroll
                for (int i = 0; i < 4; ++i)
                    stg[i] = *(const floatx4*)(x + (size_t)(b0 + i) * T_LEN * IN_DIM
                                                 + (size_t)tmap(tn) * IN_DIM + l32 * 4);
            }
        }
        if (sl == 1 && chk + 1 < NCH) {      // loads drained by sl0 barrier
#pragma unroll
            for (int i = 0; i < 4; ++i) {
                unsigned lo = (unsigned)f2bf(stg[i].x) | ((unsigned)f2bf(stg[i].y) << 16);
                unsigned hi = (unsigned)f2bf(stg[i].z) | ((unsigned)f2bf(stg[i].w) << 16);
                uintx2 p = {lo, hi};
                *(uintx2*)&xch[cbuf ^ 1][g][i * XSTR + l32 * 4] = p;
            }
        }

        // critical ds_reads first: h(t) A-frags
        short8 ha[2];
        const unsigned short* hb = &h_s[cur][(nloc >> 2) * HSTR + quad * 8];
#pragma unroll
        for (int kf = 0; kf < 2; ++kf) ha[kf] = *(const short8*)(hb + kf * 32);

        // x(t+1) A-frags: same chunk sl+1, or next chunk's slot 0 at sl==7
        short8 xa[4];
        const unsigned short* xb = (sl + 1 < CH)
            ? &xch[cbuf][sl + 1][(nloc >> 2) * XSTR + quad * 8]
            : &xch[cbuf ^ 1][0][(nloc >> 2) * XSTR + quad * 8];
#pragma unroll
        for (int kf = 0; kf < 4; ++kf) xa[kf] = *(const short8*)(xb + kf * 32);

        // critical chain: 2 h-MFMAs on top of precomputed xaccC
        floatx4 acc[4];
#pragma unroll
        for (int gc = 0; gc < 4; ++gc)
            acc[gc] = __builtin_amdgcn_mfma_f32_16x16x32_bf16(ha[0], whhf[gc][0], xaccC[gc], 0, 0, 0);
#pragma unroll
        for (int gc = 0; gc < 4; ++gc)
            acc[gc] = __builtin_amdgcn_mfma_f32_16x16x32_bf16(ha[1], whhf[gc][1], acc[gc], 0, 0, 0);

        // off-critical: input-gate accumulators for step t+1
#pragma unroll
        for (int gc = 0; gc < 4; ++gc) xaccN[gc] = (floatx4){bv[gc], bv[gc], bv[gc], bv[gc]};
#pragma unroll
        for (int kf = 0; kf < 4; ++kf)
#pragma unroll
            for (int gc = 0; gc < 4; ++gc)
                xaccN[gc] = __builtin_amdgcn_mfma_f32_16x16x32_bf16(xa[kf], wihf[gc][kf], xaccN[gc], 0, 0, 0);

        // epilogue: gates replicated across acc regs -> use [0]
        {
            float iv = sigm(acc[0][0]);
            float fv = sigm(acc[1][0]);
            float gv = tanh_(acc[2][0]);
            float ov = sigm(acc[3][0]);
            c = fv * c + iv * gv;
            float hv = ov * tanh_(c);
            obuf[cbuf][sl][quad][w * 16 + nloc] = hv;            // LDS, not global
            h_s[cur ^ 1][quad * HSTR + w * 16 + nloc] = f2bf(hv);
        }
        __syncthreads();
    };

    for (int chk = 0; chk < NCH; ++chk) {
        const int cbuf = chk & 1;
#pragma unroll
        for (int sp = 0; sp < CH; sp += 2) {
            step(sp,     chk, cbuf, xacc0, xacc1);
            step(sp + 1, chk, cbuf, xacc1, xacc0);
        }
    }
    flushPrev(NCH - 1);        // last chunk (after the loop's final barrier)
}

extern "C" void kernel_launch(void* const* d_in, const int* in_sizes, int n_in,
                              void* d_out, int out_size, void* d_ws, size_t ws_size,
                              hipStream_t stream) {
    const float* x    = (const float*)d_in[0];
    const float* WihF = (const float*)d_in[1];
    const float* WhhF = (const float*)d_in[2];
    const float* bF   = (const float*)d_in[3];
    const float* WihB = (const float*)d_in[4];
    const float* WhhB = (const float*)d_in[5];
    const float* bB   = (const float*)d_in[6];
    float* out = (float*)d_out;

    lstm_bidir<<<dim3(256), dim3(256), 0, stream>>>(x, WihF, WhhF, bF, WihB, WhhB, bB, out);
}